// Round 14
// baseline (113.508 us; speedup 1.0000x reference)
//
#include <hip/hip_runtime.h>

#define B_ 8
#define N_ 8192
#define E_ 1024
#define ROWS (B_ * N_)          // 65536
#define BE (B_ * E_)            // 8192
#define NT 10                   // 0..4 = S=(W1+W2) proj (col64=S-membrane in tile4 col0),
                                // 5..9 = Y2=W2 proj (tile9 col0 = Y2-membrane)
#define KT 8                    // K = 256

typedef float  f32x4  __attribute__((ext_vector_type(4)));
typedef __bf16 bf16x8 __attribute__((ext_vector_type(8)));

// ---- workspace layout (byte offsets) ----
#define SE16_OFF  0                            // ROWS*64 bf16 (boundary rows only)
#define SM16_OFF  (SE16_OFF + ROWS * 64 * 2)   // ROWS bf16    (boundary rows only)
#define SEG_OFF   (SM16_OFF + ROWS * 2)        // BE uint2 {start,len}
#define ORD_OFF   (SEG_OFF + BE * 8)           // ROWS u32 : sorted position -> row
#define WEF_OFF   (ORD_OFF + ROWS * 4)         // KT*NT*64*8 bf16 (80 KB)
#define GYS_OFF   (WEF_OFF + KT * NT * 64 * 8 * 2)  // BE*4 slots*66 f32 (8.7 MB)
#define GCNT_OFF  (GYS_OFF + (size_t)BE * 4 * 66 * 4) // BE u32 arrival counters

__device__ inline float bfu16(unsigned short u) { return __uint_as_float(((unsigned)u) << 16); }

// blocks 0..7: per-batch LDS bucketize (hist+scan+fill). blocks 8..12: pack W'.
// All blocks also zero gcnt.
__global__ __launch_bounds__(1024) void bucketize_kernel(
    const int* __restrict__ idx, const float* __restrict__ we,
    const float* __restrict__ wm, char* __restrict__ ws) {

    {   // zero arrival counters (re-done every launch: deterministic replays)
        unsigned* gcnt = (unsigned*)(ws + GCNT_OFF);
        const int gz = blockIdx.x * 1024 + threadIdx.x;
        if (gz < BE) gcnt[gz] = 0u;
    }

    const int bid = blockIdx.x;
    if (bid >= 8) {                            // ---- wef packing ----
        const int t = (bid - 8) * 1024 + threadIdx.x;   // 0..5119
        if (t >= KT * NT * 64) return;
        __bf16* wef = (__bf16*)(ws + WEF_OFF);
        const int lane = t & 63;
        const int nt = (t >> 6) % NT;
        const int kt = t / (NT * 64);
        const int grp = nt / 5;
        const int r   = (nt % 5) * 16 + (lane & 15);
        const int k0  = kt * 32 + (lane >> 4) * 8;
        bf16x8 v;
#pragma unroll
        for (int i = 0; i < 8; ++i) {
            const int k = k0 + i;
            float f = 0.f;
            if (r < 64)       f = grp ? we[r * 512 + 256 + k] : we[r * 512 + k] + we[r * 512 + 256 + k];
            else if (r == 64) f = grp ? wm[256 + k]           : wm[k] + wm[256 + k];
            v[i] = (__bf16)f;
        }
        *(bf16x8*)(wef + (size_t)t * 8) = v;
        return;
    }

    // ---- per-batch bucketize ----
    __shared__ unsigned h[1024];
    __shared__ unsigned wpart[16];
    const int b = bid;
    const int t = threadIdx.x;
    const int lane = t & 63;
    const int w = t >> 6;

    h[t] = 0u;
    __syncthreads();

    unsigned my[8];
#pragma unroll
    for (int i = 0; i < 8; ++i) my[i] = (unsigned)idx[(b << 13) + (i << 10) + t];
#pragma unroll
    for (int i = 0; i < 8; ++i) atomicAdd(&h[my[i]], 1u);
    __syncthreads();

    const unsigned v = h[t];
    unsigned inc = v;
#pragma unroll
    for (int off = 1; off < 64; off <<= 1) {
        const unsigned u = __shfl_up(inc, off);
        if (lane >= off) inc += u;
    }
    if (lane == 63) wpart[w] = inc;
    __syncthreads();
    unsigned add = 0;
    for (int ww = 0; ww < w; ++ww) add += wpart[ww];
    const unsigned base = add + inc - v;               // exclusive scan within batch

    ((uint2*)(ws + SEG_OFF))[(b << 10) + t] = (uint2){(unsigned)(b << 13) + base, v};
    __syncthreads();
    h[t] = base;                                       // reuse hist as cursor
    __syncthreads();

    unsigned* order = (unsigned*)(ws + ORD_OFF);
#pragma unroll
    for (int i = 0; i < 8; ++i) {
        const unsigned p = atomicAdd(&h[my[i]], 1u);
        order[(b << 13) + p] = (unsigned)((b << 13) + (i << 10) + t);
    }
}

// Fused GEMM + bucket-mean + final math. 128 sorted rows per block, 32 per wave.
// Interior buckets: everything from registers/LDS. Boundary buckets: deterministic
// slot partials + last-arriver finalizes (lock-free, any dispatch order).
__global__ __launch_bounds__(256) void gemm_fused_kernel(
    const float* __restrict__ obs, const float* __restrict__ mask,
    const int* __restrict__ idx, const float* __restrict__ bmp,
    const float* __restrict__ bep, char* __restrict__ ws,
    float* __restrict__ out) {

    __shared__ float bsum[129][66];    // block-local bucket sums (Y2 cols 0..63, 64=membrane)

    const __bf16*   wefg = (const __bf16*)(ws + WEF_OFF);
    const unsigned* ordu = (const unsigned*)(ws + ORD_OFF);
    const uint2*    seg  = (const uint2*)(ws + SEG_OFF);
    __bf16*   sE   = (__bf16*)(ws + SE16_OFF);
    __bf16*   sM   = (__bf16*)(ws + SM16_OFF);
    float*    gys  = (float*)(ws + GYS_OFF);
    unsigned* gcnt = (unsigned*)(ws + GCNT_OFF);

    const int tid    = threadIdx.x;
    const int l      = tid & 63;
    const int wv     = tid >> 6;
    const int bstart = blockIdx.x * 128;
    const int pw     = bstart + wv * 32;
    const int c16    = l & 15;
    const int cgrp   = (l >> 4) << 2;

    for (int i = tid; i < 129 * 66; i += 256) (&bsum[0][0])[i] = 0.f;
    __syncthreads();

    // per-position row/bucket/mask for this wave's 32-row window (lanes 0..31)
    unsigned row32 = 0; int bkt32 = -1; float mk32 = 0.f;
    if (l < 32) {
        row32 = ordu[pw + l];
        bkt32 = (int)(((row32 >> 13) << 10) + (unsigned)idx[row32]);
        mk32  = mask[row32];
    }
    const unsigned rA0 = __shfl(row32, c16);
    const unsigned rA1 = __shfl(row32, 16 + c16);

    const unsigned rowb0 = ordu[bstart];
    const int kb0blk = (int)(((rowb0 >> 13) << 10) + (unsigned)idx[rowb0]);

    const float bm = bmp[0];
    float bel[4];
#pragma unroll
    for (int k = 0; k < 4; ++k) bel[k] = bep[(k << 4) + c16];

    // ---- MFMA ----
    f32x4 acc[2][NT];
#pragma unroll
    for (int a = 0; a < 2; ++a)
#pragma unroll
        for (int b = 0; b < NT; ++b) acc[a][b] = (f32x4){0.f, 0.f, 0.f, 0.f};

    const int q8 = (l >> 4) << 3;
    const float* o0 = obs + (((size_t)rA0) << 8) + q8;
    const float* o1 = obs + (((size_t)rA1) << 8) + q8;

#pragma unroll
    for (int g = 0; g < KT; ++g) {
        const f32x4 oa0 = *(const f32x4*)(o0 + g * 32);
        const f32x4 ob0 = *(const f32x4*)(o0 + g * 32 + 4);
        const f32x4 oa1 = *(const f32x4*)(o1 + g * 32);
        const f32x4 ob1 = *(const f32x4*)(o1 + g * 32 + 4);
        bf16x8 A0, A1;
#pragma unroll
        for (int i = 0; i < 4; ++i) {
            A0[i] = (__bf16)oa0[i];  A0[4 + i] = (__bf16)ob0[i];
            A1[i] = (__bf16)oa1[i];  A1[4 + i] = (__bf16)ob1[i];
        }
#pragma unroll
        for (int nt = 0; nt < NT; ++nt) {
            const bf16x8 bb = *(const bf16x8*)(wefg + (size_t)(((g * NT + nt) << 6) + l) * 8);
            acc[0][nt] = __builtin_amdgcn_mfma_f32_16x16x32_bf16(A0, bb, acc[0][nt], 0, 0, 0);
            acc[1][nt] = __builtin_amdgcn_mfma_f32_16x16x32_bf16(A1, bb, acc[1][nt], 0, 0, 0);
        }
    }

    // ---- segment walk: in-register Y2 sums -> LDS; boundary rows -> global sE/sM ----
    unsigned bmsk = 0;                 // bit (rt*4+j): row is in a block-boundary bucket
    float invrow[2][4] = {{0.f,0.f,0.f,0.f},{0.f,0.f,0.f,0.f}};
    int s = 0;
    while (s < 32) {                   // wave-uniform loop
        const int bkt = __shfl(bkt32, s);
        const unsigned long long mrun = __ballot(bkt32 == bkt);   // lanes>=32: bkt32=-1 -> false
        const unsigned long long mm = ~(mrun >> s);
        const int e = s + (__ffsll((long long)mm) - 1);
        const uint2 sg = seg[bkt];
        const bool bnd = (sg.x < (unsigned)bstart) || (sg.x + sg.y > (unsigned)(bstart + 128));
        const float invf = 1.f / (float)sg.y;
        const int krel = bkt - kb0blk;

        float s0 = 0.f, s1 = 0.f, s2 = 0.f, s3 = 0.f, sm5 = 0.f;
#pragma unroll
        for (int rt = 0; rt < 2; ++rt)
#pragma unroll
            for (int j = 0; j < 4; ++j) {
                const int rr = rt * 16 + cgrp + j;
                if (rr >= s && rr < e) {
                    s0 += acc[rt][5][j]; s1 += acc[rt][6][j];
                    s2 += acc[rt][7][j]; s3 += acc[rt][8][j];
                    sm5 += acc[rt][9][j];
                    invrow[rt][j] = invf;
                    if (bnd) {
                        bmsk |= 1u << (rt * 4 + j);
                        const int pos = pw + rr;
                        sE[((size_t)pos << 6) +  0 + c16] = (__bf16)acc[rt][0][j];
                        sE[((size_t)pos << 6) + 16 + c16] = (__bf16)acc[rt][1][j];
                        sE[((size_t)pos << 6) + 32 + c16] = (__bf16)acc[rt][2][j];
                        sE[((size_t)pos << 6) + 48 + c16] = (__bf16)acc[rt][3][j];
                        if (c16 == 0) sM[pos] = (__bf16)acc[rt][4][j];
                    }
                }
            }
        s0 += __shfl_xor(s0, 16); s0 += __shfl_xor(s0, 32);
        s1 += __shfl_xor(s1, 16); s1 += __shfl_xor(s1, 32);
        s2 += __shfl_xor(s2, 16); s2 += __shfl_xor(s2, 32);
        s3 += __shfl_xor(s3, 16); s3 += __shfl_xor(s3, 32);
        sm5 += __shfl_xor(sm5, 16); sm5 += __shfl_xor(sm5, 32);
        if (l < 16) {
            atomicAdd(&bsum[krel][ 0 + c16], s0);
            atomicAdd(&bsum[krel][16 + c16], s1);
            atomicAdd(&bsum[krel][32 + c16], s2);
            atomicAdd(&bsum[krel][48 + c16], s3);
            if (l == 0) atomicAdd(&bsum[krel][64], sm5);
        }
        s = e;
    }
    __syncthreads();

    // ---- interior outputs straight from registers ----
#pragma unroll
    for (int rt = 0; rt < 2; ++rt)
#pragma unroll
        for (int j = 0; j < 4; ++j) {
            const int rr = rt * 16 + cgrp + j;
            const int krel = __shfl(bkt32, rr) - kb0blk;
            const float invf = invrow[rt][j];
            const float mM  = bsum[krel][64] * invf;
            const float sMv = __shfl(acc[rt][4][j], l & 48);
            const float mk  = __shfl(mk32, rr);
            const unsigned row = __shfl(row32, rr);
            const float g = mk / (1.f + __expf(-(sMv - mM + bm)));
            if (!((bmsk >> (rt * 4 + j)) & 1u)) {
                if (c16 == 0) out[row] = g;
#pragma unroll
                for (int k = 0; k < 4; ++k) {
                    const float mean = bsum[krel][(k << 4) + c16] * invf;
                    out[(size_t)ROWS + ((size_t)row << 6) + (k << 4) + c16] =
                        (acc[rt][k][j] - mean + bel[k]) * g * mk;
                }
            }
        }

    // ---- boundary protocol: wave 0 = head bucket, wave 3 = tail bucket ----
    int kb = -1;
    if (wv == 0) kb = kb0blk;
    if (wv == 3) {
        const int kbt = __shfl(bkt32, 31);
        kb = (kbt == kb0blk) ? -1 : kbt;
    }
    if (kb >= 0) {
        const uint2 sg = seg[kb];
        if (sg.x < (unsigned)bstart || sg.x + sg.y > (unsigned)(bstart + 128)) {
            const int krel   = kb - kb0blk;
            const int firstb = (int)(sg.x >> 7);
            const int nctr   = (int)((sg.x + sg.y - 1) >> 7) - firstb + 1;   // <=4 (len<=384)
            const int slot   = (int)blockIdx.x - firstb;
            float* slotp = gys + ((size_t)kb * 4 + slot) * 66;
            slotp[l] = bsum[krel][l];
            if (l == 0) slotp[64] = bsum[krel][64];
            __threadfence();
            unsigned old = 0;
            if (l == 0) old = atomicAdd(&gcnt[kb], 1u);
            old = __shfl(old, 0);
            if ((int)old == nctr - 1) {            // last arriver finalizes whole bucket
                __threadfence();
                float tot = 0.f, totM = 0.f;
                for (int s2 = 0; s2 < nctr; ++s2) {   // fixed order -> deterministic
                    const float* sp2 = gys + ((size_t)kb * 4 + s2) * 66;
                    tot += sp2[l];
                    if (l == 0) totM += sp2[64];
                }
                const float invf  = 1.f / (float)sg.y;
                const float meanL = tot * invf;
                const float meanM = __shfl(totM, 0) * invf;
                const unsigned short* sEu = (const unsigned short*)sE;
                const unsigned short* sMu = (const unsigned short*)sM;
                for (unsigned p = sg.x; p < sg.x + sg.y; ++p) {
                    const unsigned row = ordu[p];
                    const float mk = mask[row];
                    const float m  = bfu16(sMu[p]) - meanM + bm;
                    const float g  = mk / (1.f + __expf(-m));
                    out[(size_t)ROWS + ((size_t)row << 6) + l] =
                        (bfu16(sEu[(size_t)p * 64 + l]) - meanL + bep[l]) * g * mk;
                    if (l == 0) out[row] = g;
                }
            }
        }
    }
}

extern "C" void kernel_launch(void* const* d_in, const int* in_sizes, int n_in,
                              void* d_out, int out_size, void* d_ws, size_t ws_size,
                              hipStream_t stream) {
    (void)in_sizes; (void)n_in; (void)out_size; (void)ws_size;
    const float* obs  = (const float*)d_in[0];
    const float* mask = (const float*)d_in[1];
    // d_in[2] = incidence: one-hot of idx, never read (saves 268 MB of traffic)
    const int*   idx  = (const int*)d_in[3];
    const float* w_m  = (const float*)d_in[4];
    const float* b_m  = (const float*)d_in[5];
    const float* w_e  = (const float*)d_in[6];
    const float* b_e  = (const float*)d_in[7];

    char* ws = (char*)d_ws;

    bucketize_kernel<<<13, 1024, 0, stream>>>(idx, w_e, w_m, ws);
    gemm_fused_kernel<<<ROWS / 128, 256, 0, stream>>>(obs, mask, idx, b_m, b_e, ws,
                                                      (float*)d_out);
}

// Round 16
// 58.206 us; speedup vs baseline: 1.9501x; 1.9501x over previous
//
#include <hip/hip_runtime.h>

#define B_ 8
#define N_ 8192
#define E_ 1024
#define ROWS (B_ * N_)          // 65536
#define BE (B_ * E_)            // 8192
#define NT 10                   // 0..4 = S=(W1+W2) proj, 5..9 = Y2=W2 proj (col 64 = membrane)
#define KT 8                    // K = 256

typedef float  f32x4  __attribute__((ext_vector_type(4)));
typedef float  f32x2  __attribute__((ext_vector_type(2)));
typedef __bf16 bf16x8 __attribute__((ext_vector_type(8)));

// ---- workspace layout (byte offsets). Bulk arrays indexed by SORTED position. ----
#define SE16_OFF  0                            // ROWS*64 bf16 (8.39 MB)
#define SM16_OFF  (SE16_OFF + ROWS * 64 * 2)   // ROWS bf16
#define Y2E_OFF   (SM16_OFF + ROWS * 2)        // ROWS*64 bf16 (8.39 MB)
#define Y2M_OFF   (Y2E_OFF + ROWS * 64 * 2)    // ROWS bf16
#define SEG_OFF   (Y2M_OFF + ROWS * 2)         // BE uint2 {start,len}
#define ORD_OFF   (SEG_OFF + BE * 8)           // ROWS u32 : sorted position -> row
#define WEF_OFF   (ORD_OFF + ROWS * 4)         // KT*NT*64*8 bf16 (80 KB)

__device__ inline float bflo(unsigned u) { return __uint_as_float(u << 16); }
__device__ inline float bfhi(unsigned u) { return __uint_as_float(u & 0xffff0000u); }

// blocks 0..7: per-batch LDS bucketize (hist+scan+fill, zero global atomics).
// blocks 8..12: pack W' fragments.
// wef[((kt*NT+nt)*64+lane)*8+i] = W'[(nt%5)*16+(lane&15)][kt*32+(lane>>4)*8+i]
//   grp = nt/5: 0 -> W1+W2 (S), 1 -> W2 (Y2); row 64 = w_m, 65..79 zero.
__global__ __launch_bounds__(1024) void bucketize_kernel(
    const int* __restrict__ idx, const float* __restrict__ we,
    const float* __restrict__ wm, char* __restrict__ ws) {

    const int bid = blockIdx.x;
    if (bid >= 8) {                            // ---- wef packing ----
        const int t = (bid - 8) * 1024 + threadIdx.x;   // 0..5119
        if (t >= KT * NT * 64) return;
        __bf16* wef = (__bf16*)(ws + WEF_OFF);
        const int lane = t & 63;
        const int nt = (t >> 6) % NT;
        const int kt = t / (NT * 64);
        const int grp = nt / 5;
        const int r   = (nt % 5) * 16 + (lane & 15);
        const int k0  = kt * 32 + (lane >> 4) * 8;
        bf16x8 v;
#pragma unroll
        for (int i = 0; i < 8; ++i) {
            const int k = k0 + i;
            float f = 0.f;
            if (r < 64)       f = grp ? we[r * 512 + 256 + k] : we[r * 512 + k] + we[r * 512 + 256 + k];
            else if (r == 64) f = grp ? wm[256 + k]           : wm[k] + wm[256 + k];
            v[i] = (__bf16)f;
        }
        *(bf16x8*)(wef + (size_t)t * 8) = v;
        return;
    }

    // ---- per-batch bucketize: batch b, 1024 threads, LDS hist/scan/cursor ----
    __shared__ unsigned h[1024];
    __shared__ unsigned wpart[16];
    const int b = bid;
    const int t = threadIdx.x;
    const int lane = t & 63;
    const int w = t >> 6;

    h[t] = 0u;
    __syncthreads();

    unsigned my[8];
#pragma unroll
    for (int i = 0; i < 8; ++i) my[i] = (unsigned)idx[(b << 13) + (i << 10) + t];
#pragma unroll
    for (int i = 0; i < 8; ++i) atomicAdd(&h[my[i]], 1u);
    __syncthreads();

    const unsigned v = h[t];
    unsigned inc = v;
#pragma unroll
    for (int off = 1; off < 64; off <<= 1) {
        const unsigned u = __shfl_up(inc, off);
        if (lane >= off) inc += u;
    }
    if (lane == 63) wpart[w] = inc;
    __syncthreads();
    unsigned add = 0;
    for (int ww = 0; ww < w; ++ww) add += wpart[ww];
    const unsigned base = add + inc - v;               // exclusive scan within batch

    ((uint2*)(ws + SEG_OFF))[(b << 10) + t] = (uint2){(unsigned)(b << 13) + base, v};
    __syncthreads();
    h[t] = base;                                       // reuse hist as cursor
    __syncthreads();

    unsigned* order = (unsigned*)(ws + ORD_OFF);
#pragma unroll
    for (int i = 0; i < 8; ++i) {
        const unsigned p = atomicAdd(&h[my[i]], 1u);
        order[(b << 13) + p] = (unsigned)((b << 13) + (i << 10) + t);
    }
}

// GEMM over SORTED row order: lane gathers its obs row via order[] (random but
// full-line 128B reads, NON-TEMPORAL: obs is stream-once, keep L2 for sE/y2e);
// epilogue writes sE/sM/y2e/y2m fully contiguous at the block's sorted window.
__global__ __launch_bounds__(256) void gemm_kernel(
    const float* __restrict__ obs, char* __restrict__ ws) {

    const __bf16*   wefg = (const __bf16*)(ws + WEF_OFF);
    const unsigned* ordu = (const unsigned*)(ws + ORD_OFF);
    const int tid = threadIdx.x;
    const int l   = tid & 63;
    const int pw0 = blockIdx.x * 128 + (tid >> 6) * 32;   // sorted-position window
    const int q8  = (l >> 4) << 3;

    const unsigned r0 = ordu[pw0 + (l & 15)];             // natural rows to gather
    const unsigned r1 = ordu[pw0 + 16 + (l & 15)];

    f32x4 acc[2][NT];
#pragma unroll
    for (int a = 0; a < 2; ++a)
#pragma unroll
        for (int b = 0; b < NT; ++b) acc[a][b] = (f32x4){0.f, 0.f, 0.f, 0.f};

    const float* o0 = obs + (((size_t)r0) << 8) + q8;
    const float* o1 = obs + (((size_t)r1) << 8) + q8;

#pragma unroll
    for (int g = 0; g < KT; ++g) {
        const f32x4 oa0 = __builtin_nontemporal_load((const f32x4*)(o0 + g * 32));
        const f32x4 ob0 = __builtin_nontemporal_load((const f32x4*)(o0 + g * 32 + 4));
        const f32x4 oa1 = __builtin_nontemporal_load((const f32x4*)(o1 + g * 32));
        const f32x4 ob1 = __builtin_nontemporal_load((const f32x4*)(o1 + g * 32 + 4));
        bf16x8 A0, A1;
#pragma unroll
        for (int i = 0; i < 4; ++i) {
            A0[i] = (__bf16)oa0[i];  A0[4 + i] = (__bf16)ob0[i];
            A1[i] = (__bf16)oa1[i];  A1[4 + i] = (__bf16)ob1[i];
        }
#pragma unroll
        for (int nt = 0; nt < NT; ++nt) {
            const bf16x8 bb = *(const bf16x8*)(wefg + (size_t)(((g * NT + nt) << 6) + l) * 8);
            acc[0][nt] = __builtin_amdgcn_mfma_f32_16x16x32_bf16(A0, bb, acc[0][nt], 0, 0, 0);
            acc[1][nt] = __builtin_amdgcn_mfma_f32_16x16x32_bf16(A1, bb, acc[1][nt], 0, 0, 0);
        }
    }

    __bf16* sE  = (__bf16*)(ws + SE16_OFF);
    __bf16* sM  = (__bf16*)(ws + SM16_OFF);
    __bf16* y2e = (__bf16*)(ws + Y2E_OFF);
    __bf16* y2m = (__bf16*)(ws + Y2M_OFF);

    const int cgrp = (l >> 4) << 2;
    const int c16  = l & 15;
#pragma unroll
    for (int rt = 0; rt < 2; ++rt) {
#pragma unroll
        for (int j = 0; j < 4; ++j) {
            const int dp = pw0 + rt * 16 + cgrp + j;       // dest = sorted position
#pragma unroll
            for (int nt = 0; nt < 4; ++nt) {
                sE [((size_t)dp << 6) + (nt << 4) + c16] = (__bf16)acc[rt][nt][j];
                y2e[((size_t)dp << 6) + (nt << 4) + c16] = (__bf16)acc[rt][5 + nt][j];
            }
            if (c16 == 0) {
                sM [dp] = (__bf16)acc[rt][4][j];
                y2m[dp] = (__bf16)acc[rt][9][j];
            }
        }
    }
}

// tail: one wave per bucket. Phase 1: contiguous segment-sum of y2 -> in-register means.
// Phase 2: final math for member rows; out stores NON-TEMPORAL (never re-read).
__global__ __launch_bounds__(256) void tail_kernel(
    const float* __restrict__ mask, const float* __restrict__ bmp,
    const float* __restrict__ bep, const char* __restrict__ ws,
    float* __restrict__ out) {

    const int bucket = blockIdx.x * 4 + (threadIdx.x >> 6);
    const int l  = threadIdx.x & 63;
    const int lc = l & 31;          // col pair (2lc, 2lc+1)
    const int hi = l >> 5;          // member parity

    const uint2 sg = ((const uint2*)(ws + SEG_OFF))[bucket];
    const unsigned start = sg.x, len = sg.y;
    if (len == 0) return;                              // wave-uniform, safe

    const unsigned*       y2eu = (const unsigned*)(ws + Y2E_OFF);
    const unsigned short* y2m  = (const unsigned short*)(ws + Y2M_OFF);

    float ax = 0.f, ay = 0.f;
    for (unsigned i = hi; i < len; i += 2) {
        const unsigned u = y2eu[(size_t)(start + i) * 32 + lc];
        ax += bflo(u); ay += bfhi(u);
    }
    ax += __shfl_xor(ax, 32);
    ay += __shfl_xor(ay, 32);

    float mm = 0.f;
    for (unsigned i = l; i < len; i += 64) mm += bflo(y2m[start + i]);
#pragma unroll
    for (int off = 1; off < 64; off <<= 1) mm += __shfl_xor(mm, off);

    const float inv = 1.f / (float)len;
    const float meL = ax * inv, meH = ay * inv, mM = mm * inv;
    const float bm  = bmp[0];
    const float beL = bep[2 * lc], beH = bep[2 * lc + 1];

    const unsigned*       sEu  = (const unsigned*)(ws + SE16_OFF);
    const unsigned short* sM16 = (const unsigned short*)(ws + SM16_OFF);
    const unsigned*       ordu = (const unsigned*)(ws + ORD_OFF);

    for (unsigned i = hi; i < len; i += 2) {
        const unsigned d   = start + i;
        const unsigned row = ordu[d];
        const unsigned u   = sEu[(size_t)d * 32 + lc];
        const float sm = bflo(sM16[d]);
        const float mk = mask[row];
        const float m  = sm - mM + bm;
        const float g  = mk / (1.f + __expf(-m));
        f32x2 e;
        e.x = (bflo(u) - meL + beL) * g * mk;
        e.y = (bfhi(u) - meH + beH) * g * mk;
        __builtin_nontemporal_store(e, (f32x2*)(out + (size_t)ROWS + ((size_t)row << 6) + 2 * lc));
        if (lc == 0) __builtin_nontemporal_store(g, out + row);
    }
}

extern "C" void kernel_launch(void* const* d_in, const int* in_sizes, int n_in,
                              void* d_out, int out_size, void* d_ws, size_t ws_size,
                              hipStream_t stream) {
    (void)in_sizes; (void)n_in; (void)out_size; (void)ws_size;
    const float* obs  = (const float*)d_in[0];
    const float* mask = (const float*)d_in[1];
    // d_in[2] = incidence: one-hot of idx, never read (saves 268 MB of traffic)
    const int*   idx  = (const int*)d_in[3];
    const float* w_m  = (const float*)d_in[4];
    const float* b_m  = (const float*)d_in[5];
    const float* w_e  = (const float*)d_in[6];
    const float* b_e  = (const float*)d_in[7];

    char* ws = (char*)d_ws;

    bucketize_kernel<<<13, 1024, 0, stream>>>(idx, w_e, w_m, ws);
    gemm_kernel<<<ROWS / 128, 256, 0, stream>>>(obs, ws);
    tail_kernel<<<BE / 4, 256, 0, stream>>>(mask, b_m, b_e, ws, (float*)d_out);
}

// Round 17
// 46.015 us; speedup vs baseline: 2.4668x; 1.2650x over previous
//
#include <hip/hip_runtime.h>

#define B_ 8
#define N_ 8192
#define E_ 1024
#define ROWS (B_ * N_)          // 65536
#define BE (B_ * E_)            // 8192
#define NT 10                   // 0..4 = S=(W1+W2) proj, 5..9 = Y2=W2 proj (col 64 = membrane)
#define KT 8                    // K = 256

typedef float  f32x4  __attribute__((ext_vector_type(4)));
typedef __bf16 bf16x8 __attribute__((ext_vector_type(8)));

// ---- workspace layout (byte offsets). Bulk arrays indexed by SORTED position. ----
#define SE16_OFF  0                            // ROWS*64 bf16 (8.39 MB)
#define SM16_OFF  (SE16_OFF + ROWS * 64 * 2)   // ROWS bf16
#define Y2E_OFF   (SM16_OFF + ROWS * 2)        // ROWS*64 bf16 (8.39 MB)
#define Y2M_OFF   (Y2E_OFF + ROWS * 64 * 2)    // ROWS bf16
#define SEG_OFF   (Y2M_OFF + ROWS * 2)         // BE uint2 {start,len}
#define ORD_OFF   (SEG_OFF + BE * 8)           // ROWS u32 : sorted position -> row
#define WEF_OFF   (ORD_OFF + ROWS * 4)         // KT*NT*64*8 bf16 (80 KB)

__device__ inline float bflo(unsigned u) { return __uint_as_float(u << 16); }
__device__ inline float bfhi(unsigned u) { return __uint_as_float(u & 0xffff0000u); }

// blocks 0..7: per-batch LDS bucketize (hist+scan+fill, zero global atomics).
// blocks 8..12: pack W' fragments.
// wef[((kt*NT+nt)*64+lane)*8+i] = W'[(nt%5)*16+(lane&15)][kt*32+(lane>>4)*8+i]
//   grp = nt/5: 0 -> W1+W2 (S), 1 -> W2 (Y2); row 64 = w_m, 65..79 zero.
__global__ __launch_bounds__(1024) void bucketize_kernel(
    const int* __restrict__ idx, const float* __restrict__ we,
    const float* __restrict__ wm, char* __restrict__ ws) {

    const int bid = blockIdx.x;
    if (bid >= 8) {                            // ---- wef packing ----
        const int t = (bid - 8) * 1024 + threadIdx.x;   // 0..5119
        if (t >= KT * NT * 64) return;
        __bf16* wef = (__bf16*)(ws + WEF_OFF);
        const int lane = t & 63;
        const int nt = (t >> 6) % NT;
        const int kt = t / (NT * 64);
        const int grp = nt / 5;
        const int r   = (nt % 5) * 16 + (lane & 15);
        const int k0  = kt * 32 + (lane >> 4) * 8;
        bf16x8 v;
#pragma unroll
        for (int i = 0; i < 8; ++i) {
            const int k = k0 + i;
            float f = 0.f;
            if (r < 64)       f = grp ? we[r * 512 + 256 + k] : we[r * 512 + k] + we[r * 512 + 256 + k];
            else if (r == 64) f = grp ? wm[256 + k]           : wm[k] + wm[256 + k];
            v[i] = (__bf16)f;
        }
        *(bf16x8*)(wef + (size_t)t * 8) = v;
        return;
    }

    // ---- per-batch bucketize: batch b, 1024 threads, LDS hist/scan/cursor ----
    __shared__ unsigned h[1024];
    __shared__ unsigned wpart[16];
    const int b = bid;
    const int t = threadIdx.x;
    const int lane = t & 63;
    const int w = t >> 6;

    h[t] = 0u;
    __syncthreads();

    unsigned my[8];
#pragma unroll
    for (int i = 0; i < 8; ++i) my[i] = (unsigned)idx[(b << 13) + (i << 10) + t];
#pragma unroll
    for (int i = 0; i < 8; ++i) atomicAdd(&h[my[i]], 1u);
    __syncthreads();

    const unsigned v = h[t];
    unsigned inc = v;
#pragma unroll
    for (int off = 1; off < 64; off <<= 1) {
        const unsigned u = __shfl_up(inc, off);
        if (lane >= off) inc += u;
    }
    if (lane == 63) wpart[w] = inc;
    __syncthreads();
    unsigned add = 0;
    for (int ww = 0; ww < w; ++ww) add += wpart[ww];
    const unsigned base = add + inc - v;               // exclusive scan within batch

    ((uint2*)(ws + SEG_OFF))[(b << 10) + t] = (uint2){(unsigned)(b << 13) + base, v};
    __syncthreads();
    h[t] = base;                                       // reuse hist as cursor
    __syncthreads();

    unsigned* order = (unsigned*)(ws + ORD_OFF);
#pragma unroll
    for (int i = 0; i < 8; ++i) {
        const unsigned p = atomicAdd(&h[my[i]], 1u);
        order[(b << 13) + p] = (unsigned)((b << 13) + (i << 10) + t);
    }
}

// GEMM over SORTED row order: lane gathers its obs row via order[] (random but
// full-line 128B reads); epilogue writes sE/sM/y2e/y2m fully contiguous at the
// block's sorted-position window. No scatter, no write-allocate waste.
__global__ __launch_bounds__(256) void gemm_kernel(
    const float* __restrict__ obs, char* __restrict__ ws) {

    const __bf16*   wefg = (const __bf16*)(ws + WEF_OFF);
    const unsigned* ordu = (const unsigned*)(ws + ORD_OFF);
    const int tid = threadIdx.x;
    const int l   = tid & 63;
    const int pw0 = blockIdx.x * 128 + (tid >> 6) * 32;   // sorted-position window
    const int q8  = (l >> 4) << 3;

    const unsigned r0 = ordu[pw0 + (l & 15)];             // natural rows to gather
    const unsigned r1 = ordu[pw0 + 16 + (l & 15)];

    f32x4 acc[2][NT];
#pragma unroll
    for (int a = 0; a < 2; ++a)
#pragma unroll
        for (int b = 0; b < NT; ++b) acc[a][b] = (f32x4){0.f, 0.f, 0.f, 0.f};

    const float* o0 = obs + (((size_t)r0) << 8) + q8;
    const float* o1 = obs + (((size_t)r1) << 8) + q8;

#pragma unroll
    for (int g = 0; g < KT; ++g) {
        const f32x4 oa0 = *(const f32x4*)(o0 + g * 32);
        const f32x4 ob0 = *(const f32x4*)(o0 + g * 32 + 4);
        const f32x4 oa1 = *(const f32x4*)(o1 + g * 32);
        const f32x4 ob1 = *(const f32x4*)(o1 + g * 32 + 4);
        bf16x8 A0, A1;
#pragma unroll
        for (int i = 0; i < 4; ++i) {
            A0[i] = (__bf16)oa0[i];  A0[4 + i] = (__bf16)ob0[i];
            A1[i] = (__bf16)oa1[i];  A1[4 + i] = (__bf16)ob1[i];
        }
#pragma unroll
        for (int nt = 0; nt < NT; ++nt) {
            const bf16x8 bb = *(const bf16x8*)(wefg + (size_t)(((g * NT + nt) << 6) + l) * 8);
            acc[0][nt] = __builtin_amdgcn_mfma_f32_16x16x32_bf16(A0, bb, acc[0][nt], 0, 0, 0);
            acc[1][nt] = __builtin_amdgcn_mfma_f32_16x16x32_bf16(A1, bb, acc[1][nt], 0, 0, 0);
        }
    }

    __bf16* sE  = (__bf16*)(ws + SE16_OFF);
    __bf16* sM  = (__bf16*)(ws + SM16_OFF);
    __bf16* y2e = (__bf16*)(ws + Y2E_OFF);
    __bf16* y2m = (__bf16*)(ws + Y2M_OFF);

    const int cgrp = (l >> 4) << 2;
    const int c16  = l & 15;
#pragma unroll
    for (int rt = 0; rt < 2; ++rt) {
#pragma unroll
        for (int j = 0; j < 4; ++j) {
            const int dp = pw0 + rt * 16 + cgrp + j;       // dest = sorted position
#pragma unroll
            for (int nt = 0; nt < 4; ++nt) {
                sE [((size_t)dp << 6) + (nt << 4) + c16] = (__bf16)acc[rt][nt][j];
                y2e[((size_t)dp << 6) + (nt << 4) + c16] = (__bf16)acc[rt][5 + nt][j];
            }
            if (c16 == 0) {
                sM [dp] = (__bf16)acc[rt][4][j];
                y2m[dp] = (__bf16)acc[rt][9][j];
            }
        }
    }
}

// tail: one wave per bucket. Phase 1: contiguous segment-sum of y2 -> in-register means.
// Phase 2: apply final math to the bucket's member rows and write g_n / e_n.
__global__ __launch_bounds__(256) void tail_kernel(
    const float* __restrict__ mask, const float* __restrict__ bmp,
    const float* __restrict__ bep, const char* __restrict__ ws,
    float* __restrict__ out) {

    const int bucket = blockIdx.x * 4 + (threadIdx.x >> 6);
    const int l  = threadIdx.x & 63;
    const int lc = l & 31;          // col pair (2lc, 2lc+1)
    const int hi = l >> 5;          // member parity

    const uint2 sg = ((const uint2*)(ws + SEG_OFF))[bucket];
    const unsigned start = sg.x, len = sg.y;
    if (len == 0) return;                              // wave-uniform, safe

    const unsigned*       y2eu = (const unsigned*)(ws + Y2E_OFF);
    const unsigned short* y2m  = (const unsigned short*)(ws + Y2M_OFF);

    float ax = 0.f, ay = 0.f;
    for (unsigned i = hi; i < len; i += 2) {
        const unsigned u = y2eu[(size_t)(start + i) * 32 + lc];
        ax += bflo(u); ay += bfhi(u);
    }
    ax += __shfl_xor(ax, 32);
    ay += __shfl_xor(ay, 32);

    float mm = 0.f;
    for (unsigned i = l; i < len; i += 64) mm += bflo(y2m[start + i]);
#pragma unroll
    for (int off = 1; off < 64; off <<= 1) mm += __shfl_xor(mm, off);

    const float inv = 1.f / (float)len;
    const float meL = ax * inv, meH = ay * inv, mM = mm * inv;
    const float bm  = bmp[0];
    const float beL = bep[2 * lc], beH = bep[2 * lc + 1];

    const unsigned*       sEu  = (const unsigned*)(ws + SE16_OFF);
    const unsigned short* sM16 = (const unsigned short*)(ws + SM16_OFF);
    const unsigned*       ordu = (const unsigned*)(ws + ORD_OFF);

    for (unsigned i = hi; i < len; i += 2) {
        const unsigned d   = start + i;
        const unsigned row = ordu[d];
        const unsigned u   = sEu[(size_t)d * 32 + lc];
        const float sm = bflo(sM16[d]);
        const float mk = mask[row];
        const float m  = sm - mM + bm;
        const float g  = mk / (1.f + __expf(-m));
        float2 e;
        e.x = (bflo(u) - meL + beL) * g * mk;
        e.y = (bfhi(u) - meH + beH) * g * mk;
        *(float2*)(out + (size_t)ROWS + ((size_t)row << 6) + 2 * lc) = e;
        if (lc == 0) out[row] = g;
    }
}

extern "C" void kernel_launch(void* const* d_in, const int* in_sizes, int n_in,
                              void* d_out, int out_size, void* d_ws, size_t ws_size,
                              hipStream_t stream) {
    (void)in_sizes; (void)n_in; (void)out_size; (void)ws_size;
    const float* obs  = (const float*)d_in[0];
    const float* mask = (const float*)d_in[1];
    // d_in[2] = incidence: one-hot of idx, never read (saves 268 MB of traffic)
    const int*   idx  = (const int*)d_in[3];
    const float* w_m  = (const float*)d_in[4];
    const float* b_m  = (const float*)d_in[5];
    const float* w_e  = (const float*)d_in[6];
    const float* b_e  = (const float*)d_in[7];

    char* ws = (char*)d_ws;

    bucketize_kernel<<<13, 1024, 0, stream>>>(idx, w_e, w_m, ws);
    gemm_kernel<<<ROWS / 128, 256, 0, stream>>>(obs, ws);
    tail_kernel<<<BE / 4, 256, 0, stream>>>(mask, b_m, b_e, ws, (float*)d_out);
}

// Round 18
// 44.113 us; speedup vs baseline: 2.5731x; 1.0431x over previous
//
#include <hip/hip_runtime.h>

#define B_ 8
#define N_ 8192
#define E_ 1024
#define ROWS (B_ * N_)          // 65536
#define BE (B_ * E_)            // 8192
#define NT 10                   // 0..4 = S=(W1+W2) proj, 5..9 = Y2=W2 proj (col 64 = membrane)
#define KT 8                    // K = 256

typedef float  f32x4  __attribute__((ext_vector_type(4)));
typedef __bf16 bf16x8 __attribute__((ext_vector_type(8)));

// ---- workspace layout (byte offsets). Bulk arrays indexed by SORTED position. ----
#define SE16_OFF  0                            // ROWS*64 bf16 (8.39 MB)
#define SM16_OFF  (SE16_OFF + ROWS * 64 * 2)   // ROWS bf16
#define Y2E_OFF   (SM16_OFF + ROWS * 2)        // ROWS*64 bf16 (8.39 MB)
#define Y2M_OFF   (Y2E_OFF + ROWS * 64 * 2)    // ROWS bf16
#define SEG_OFF   (Y2M_OFF + ROWS * 2)         // BE uint2 {start,len}
#define ORD_OFF   (SEG_OFF + BE * 8)           // ROWS u32 : sorted position -> row
#define WEF_OFF   (ORD_OFF + ROWS * 4)         // KT*NT*64*8 bf16 (80 KB)

__device__ inline float bflo(unsigned u) { return __uint_as_float(u << 16); }
__device__ inline float bfhi(unsigned u) { return __uint_as_float(u & 0xffff0000u); }

// blocks 0..7: per-batch LDS bucketize (hist+scan+fill, zero global atomics).
// blocks 8..12: pack W' fragments.
// wef[((kt*NT+nt)*64+lane)*8+i] = W'[(nt%5)*16+(lane&15)][kt*32+(lane>>4)*8+i]
//   grp = nt/5: 0 -> W1+W2 (S), 1 -> W2 (Y2); row 64 = w_m, 65..79 zero.
__global__ __launch_bounds__(1024) void bucketize_kernel(
    const int* __restrict__ idx, const float* __restrict__ we,
    const float* __restrict__ wm, char* __restrict__ ws) {

    const int bid = blockIdx.x;
    if (bid >= 8) {                            // ---- wef packing ----
        const int t = (bid - 8) * 1024 + threadIdx.x;   // 0..5119
        if (t >= KT * NT * 64) return;
        __bf16* wef = (__bf16*)(ws + WEF_OFF);
        const int lane = t & 63;
        const int nt = (t >> 6) % NT;
        const int kt = t / (NT * 64);
        const int grp = nt / 5;
        const int r   = (nt % 5) * 16 + (lane & 15);
        const int k0  = kt * 32 + (lane >> 4) * 8;
        bf16x8 v;
#pragma unroll
        for (int i = 0; i < 8; ++i) {
            const int k = k0 + i;
            float f = 0.f;
            if (r < 64)       f = grp ? we[r * 512 + 256 + k] : we[r * 512 + k] + we[r * 512 + 256 + k];
            else if (r == 64) f = grp ? wm[256 + k]           : wm[k] + wm[256 + k];
            v[i] = (__bf16)f;
        }
        *(bf16x8*)(wef + (size_t)t * 8) = v;
        return;
    }

    // ---- per-batch bucketize: batch b, 1024 threads, LDS hist/scan/cursor ----
    __shared__ unsigned h[1024];
    __shared__ unsigned wpart[16];
    const int b = bid;
    const int t = threadIdx.x;
    const int lane = t & 63;
    const int w = t >> 6;

    h[t] = 0u;
    __syncthreads();

    unsigned my[8];
#pragma unroll
    for (int i = 0; i < 8; ++i) my[i] = (unsigned)idx[(b << 13) + (i << 10) + t];
#pragma unroll
    for (int i = 0; i < 8; ++i) atomicAdd(&h[my[i]], 1u);
    __syncthreads();

    const unsigned v = h[t];
    unsigned inc = v;
#pragma unroll
    for (int off = 1; off < 64; off <<= 1) {
        const unsigned u = __shfl_up(inc, off);
        if (lane >= off) inc += u;
    }
    if (lane == 63) wpart[w] = inc;
    __syncthreads();
    unsigned add = 0;
    for (int ww = 0; ww < w; ++ww) add += wpart[ww];
    const unsigned base = add + inc - v;               // exclusive scan within batch

    ((uint2*)(ws + SEG_OFF))[(b << 10) + t] = (uint2){(unsigned)(b << 13) + base, v};
    __syncthreads();
    h[t] = base;                                       // reuse hist as cursor
    __syncthreads();

    unsigned* order = (unsigned*)(ws + ORD_OFF);
#pragma unroll
    for (int i = 0; i < 8; ++i) {
        const unsigned p = atomicAdd(&h[my[i]], 1u);
        order[(b << 13) + p] = (unsigned)((b << 13) + (i << 10) + t);
    }
}

// GEMM over SORTED row order: lane gathers its obs row via order[] (full-line 128B
// reads); B-fragments staged in LDS per K-half (block loads wef once instead of
// each wave reading 80KB from L2 -> 4x less L2 traffic, ds_read_b128 conflict-free);
// epilogue writes sE/sM/y2e/y2m fully contiguous at the block's sorted window.
__global__ __launch_bounds__(256) void gemm_kernel(
    const float* __restrict__ obs, char* __restrict__ ws) {

    __shared__ bf16x8 wefl[4 * NT * 64];   // 40 KB: one K-half of W' fragments

    const __bf16*   wefg = (const __bf16*)(ws + WEF_OFF);
    const unsigned* ordu = (const unsigned*)(ws + ORD_OFF);
    const int tid = threadIdx.x;
    const int l   = tid & 63;
    const int pw0 = blockIdx.x * 128 + (tid >> 6) * 32;   // sorted-position window
    const int q8  = (l >> 4) << 3;

    const unsigned r0 = ordu[pw0 + (l & 15)];             // natural rows to gather
    const unsigned r1 = ordu[pw0 + 16 + (l & 15)];

    f32x4 acc[2][NT];
#pragma unroll
    for (int a = 0; a < 2; ++a)
#pragma unroll
        for (int b = 0; b < NT; ++b) acc[a][b] = (f32x4){0.f, 0.f, 0.f, 0.f};

    const float* o0 = obs + (((size_t)r0) << 8) + q8;
    const float* o1 = obs + (((size_t)r1) << 8) + q8;

#pragma unroll
    for (int hf = 0; hf < 2; ++hf) {
        if (hf) __syncthreads();           // all waves done with previous half
#pragma unroll
        for (int i = 0; i < 10; ++i)       // stage 40KB: 2560 x 16B, coalesced
            wefl[i * 256 + tid] = *(const bf16x8*)(wefg + ((size_t)(hf * 2560 + i * 256 + tid)) * 8);
        __syncthreads();

#pragma unroll
        for (int g = 0; g < 4; ++g) {
            const int gg = hf * 4 + g;
            const f32x4 oa0 = *(const f32x4*)(o0 + gg * 32);
            const f32x4 ob0 = *(const f32x4*)(o0 + gg * 32 + 4);
            const f32x4 oa1 = *(const f32x4*)(o1 + gg * 32);
            const f32x4 ob1 = *(const f32x4*)(o1 + gg * 32 + 4);
            bf16x8 A0, A1;
#pragma unroll
            for (int i = 0; i < 4; ++i) {
                A0[i] = (__bf16)oa0[i];  A0[4 + i] = (__bf16)ob0[i];
                A1[i] = (__bf16)oa1[i];  A1[4 + i] = (__bf16)ob1[i];
            }
#pragma unroll
            for (int nt = 0; nt < NT; ++nt) {
                const bf16x8 bb = wefl[((g * NT + nt) << 6) + l];
                acc[0][nt] = __builtin_amdgcn_mfma_f32_16x16x32_bf16(A0, bb, acc[0][nt], 0, 0, 0);
                acc[1][nt] = __builtin_amdgcn_mfma_f32_16x16x32_bf16(A1, bb, acc[1][nt], 0, 0, 0);
            }
        }
    }

    __bf16* sE  = (__bf16*)(ws + SE16_OFF);
    __bf16* sM  = (__bf16*)(ws + SM16_OFF);
    __bf16* y2e = (__bf16*)(ws + Y2E_OFF);
    __bf16* y2m = (__bf16*)(ws + Y2M_OFF);

    const int cgrp = (l >> 4) << 2;
    const int c16  = l & 15;
#pragma unroll
    for (int rt = 0; rt < 2; ++rt) {
#pragma unroll
        for (int j = 0; j < 4; ++j) {
            const int dp = pw0 + rt * 16 + cgrp + j;       // dest = sorted position
#pragma unroll
            for (int nt = 0; nt < 4; ++nt) {
                sE [((size_t)dp << 6) + (nt << 4) + c16] = (__bf16)acc[rt][nt][j];
                y2e[((size_t)dp << 6) + (nt << 4) + c16] = (__bf16)acc[rt][5 + nt][j];
            }
            if (c16 == 0) {
                sM [dp] = (__bf16)acc[rt][4][j];
                y2m[dp] = (__bf16)acc[rt][9][j];
            }
        }
    }
}

// tail: one wave per bucket. Phase 1: contiguous segment-sum of y2 -> in-register means.
// Phase 2: apply final math to the bucket's member rows and write g_n / e_n.
__global__ __launch_bounds__(256) void tail_kernel(
    const float* __restrict__ mask, const float* __restrict__ bmp,
    const float* __restrict__ bep, const char* __restrict__ ws,
    float* __restrict__ out) {

    const int bucket = blockIdx.x * 4 + (threadIdx.x >> 6);
    const int l  = threadIdx.x & 63;
    const int lc = l & 31;          // col pair (2lc, 2lc+1)
    const int hi = l >> 5;          // member parity

    const uint2 sg = ((const uint2*)(ws + SEG_OFF))[bucket];
    const unsigned start = sg.x, len = sg.y;
    if (len == 0) return;                              // wave-uniform, safe

    const unsigned*       y2eu = (const unsigned*)(ws + Y2E_OFF);
    const unsigned short* y2m  = (const unsigned short*)(ws + Y2M_OFF);

    float ax = 0.f, ay = 0.f;
    for (unsigned i = hi; i < len; i += 2) {
        const unsigned u = y2eu[(size_t)(start + i) * 32 + lc];
        ax += bflo(u); ay += bfhi(u);
    }
    ax += __shfl_xor(ax, 32);
    ay += __shfl_xor(ay, 32);

    float mm = 0.f;
    for (unsigned i = l; i < len; i += 64) mm += bflo(y2m[start + i]);
#pragma unroll
    for (int off = 1; off < 64; off <<= 1) mm += __shfl_xor(mm, off);

    const float inv = 1.f / (float)len;
    const float meL = ax * inv, meH = ay * inv, mM = mm * inv;
    const float bm  = bmp[0];
    const float beL = bep[2 * lc], beH = bep[2 * lc + 1];

    const unsigned*       sEu  = (const unsigned*)(ws + SE16_OFF);
    const unsigned short* sM16 = (const unsigned short*)(ws + SM16_OFF);
    const unsigned*       ordu = (const unsigned*)(ws + ORD_OFF);

    for (unsigned i = hi; i < len; i += 2) {
        const unsigned d   = start + i;
        const unsigned row = ordu[d];
        const unsigned u   = sEu[(size_t)d * 32 + lc];
        const float sm = bflo(sM16[d]);
        const float mk = mask[row];
        const float m  = sm - mM + bm;
        const float g  = mk / (1.f + __expf(-m));
        float2 e;
        e.x = (bflo(u) - meL + beL) * g * mk;
        e.y = (bfhi(u) - meH + beH) * g * mk;
        *(float2*)(out + (size_t)ROWS + ((size_t)row << 6) + 2 * lc) = e;
        if (lc == 0) out[row] = g;
    }
}

extern "C" void kernel_launch(void* const* d_in, const int* in_sizes, int n_in,
                              void* d_out, int out_size, void* d_ws, size_t ws_size,
                              hipStream_t stream) {
    (void)in_sizes; (void)n_in; (void)out_size; (void)ws_size;
    const float* obs  = (const float*)d_in[0];
    const float* mask = (const float*)d_in[1];
    // d_in[2] = incidence: one-hot of idx, never read (saves 268 MB of traffic)
    const int*   idx  = (const int*)d_in[3];
    const float* w_m  = (const float*)d_in[4];
    const float* b_m  = (const float*)d_in[5];
    const float* w_e  = (const float*)d_in[6];
    const float* b_e  = (const float*)d_in[7];

    char* ws = (char*)d_ws;

    bucketize_kernel<<<13, 1024, 0, stream>>>(idx, w_e, w_m, ws);
    gemm_kernel<<<ROWS / 128, 256, 0, stream>>>(obs, ws);
    tail_kernel<<<BE / 4, 256, 0, stream>>>(mask, b_m, b_e, ws, (float*)d_out);
}

// Round 19
// 43.839 us; speedup vs baseline: 2.5892x; 1.0062x over previous
//
#include <hip/hip_runtime.h>

#define B_ 8
#define N_ 8192
#define E_ 1024
#define ROWS (B_ * N_)          // 65536
#define BE (B_ * E_)            // 8192
#define NT 10                   // 0..4 = S=(W1+W2) proj, 5..9 = Y2=W2 proj (col 64 = membrane)
#define KT 8                    // K = 256

typedef float  f32x4  __attribute__((ext_vector_type(4)));
typedef __bf16 bf16x8 __attribute__((ext_vector_type(8)));

// ---- workspace layout (byte offsets). Bulk arrays indexed by SORTED position. ----
// su[pos*64+col] = u32 {lo = sE bf16, hi = y2e bf16}  (16.8 MB)
#define SU_OFF   0
#define SMU_OFF  (SU_OFF + (size_t)ROWS * 64 * 4)     // ROWS u32 {lo = sM, hi = y2m}
#define SEG_OFF  (SMU_OFF + ROWS * 4)                 // BE uint2 {start,len}
#define ORD_OFF  (SEG_OFF + BE * 8)                   // ROWS u32 : sorted position -> row
#define WEF_OFF  (ORD_OFF + ROWS * 4)                 // KT*NT*64*8 bf16 (80 KB)

__device__ inline float bflo(unsigned u) { return __uint_as_float(u << 16); }
__device__ inline float bfhi(unsigned u) { return __uint_as_float(u & 0xffff0000u); }
__device__ inline unsigned pack2(float lo, float hi) {
    return (unsigned)__builtin_bit_cast(unsigned short, (__bf16)lo)
         | ((unsigned)__builtin_bit_cast(unsigned short, (__bf16)hi) << 16);
}

// blocks 0..7: per-batch LDS bucketize (hist+scan+fill, zero global atomics).
// blocks 8..12: pack W' fragments.
// wef[((kt*NT+nt)*64+lane)*8+i] = W'[(nt%5)*16+(lane&15)][kt*32+(lane>>4)*8+i]
//   grp = nt/5: 0 -> W1+W2 (S), 1 -> W2 (Y2); row 64 = w_m, 65..79 zero.
__global__ __launch_bounds__(1024) void bucketize_kernel(
    const int* __restrict__ idx, const float* __restrict__ we,
    const float* __restrict__ wm, char* __restrict__ ws) {

    const int bid = blockIdx.x;
    if (bid >= 8) {                            // ---- wef packing ----
        const int t = (bid - 8) * 1024 + threadIdx.x;   // 0..5119
        if (t >= KT * NT * 64) return;
        __bf16* wef = (__bf16*)(ws + WEF_OFF);
        const int lane = t & 63;
        const int nt = (t >> 6) % NT;
        const int kt = t / (NT * 64);
        const int grp = nt / 5;
        const int r   = (nt % 5) * 16 + (lane & 15);
        const int k0  = kt * 32 + (lane >> 4) * 8;
        bf16x8 v;
#pragma unroll
        for (int i = 0; i < 8; ++i) {
            const int k = k0 + i;
            float f = 0.f;
            if (r < 64)       f = grp ? we[r * 512 + 256 + k] : we[r * 512 + k] + we[r * 512 + 256 + k];
            else if (r == 64) f = grp ? wm[256 + k]           : wm[k] + wm[256 + k];
            v[i] = (__bf16)f;
        }
        *(bf16x8*)(wef + (size_t)t * 8) = v;
        return;
    }

    // ---- per-batch bucketize: batch b, 1024 threads, LDS hist/scan/cursor ----
    __shared__ unsigned h[1024];
    __shared__ unsigned wpart[16];
    const int b = bid;
    const int t = threadIdx.x;
    const int lane = t & 63;
    const int w = t >> 6;

    h[t] = 0u;
    __syncthreads();

    unsigned my[8];
#pragma unroll
    for (int i = 0; i < 8; ++i) my[i] = (unsigned)idx[(b << 13) + (i << 10) + t];
#pragma unroll
    for (int i = 0; i < 8; ++i) atomicAdd(&h[my[i]], 1u);
    __syncthreads();

    const unsigned v = h[t];
    unsigned inc = v;
#pragma unroll
    for (int off = 1; off < 64; off <<= 1) {
        const unsigned u = __shfl_up(inc, off);
        if (lane >= off) inc += u;
    }
    if (lane == 63) wpart[w] = inc;
    __syncthreads();
    unsigned add = 0;
    for (int ww = 0; ww < w; ++ww) add += wpart[ww];
    const unsigned base = add + inc - v;               // exclusive scan within batch

    ((uint2*)(ws + SEG_OFF))[(b << 10) + t] = (uint2){(unsigned)(b << 13) + base, v};
    __syncthreads();
    h[t] = base;                                       // reuse hist as cursor
    __syncthreads();

    unsigned* order = (unsigned*)(ws + ORD_OFF);
#pragma unroll
    for (int i = 0; i < 8; ++i) {
        const unsigned p = atomicAdd(&h[my[i]], 1u);
        order[(b << 13) + p] = (unsigned)((b << 13) + (i << 10) + t);
    }
}

// GEMM over SORTED row order: lane gathers its obs row via order[] (full-line 128B
// reads); B-fragments staged in LDS per K-half (R18 win); epilogue writes PACKED
// su (sE|y2e u32) + smu (sM|y2m) fully contiguous -> 256B per store instruction.
__global__ __launch_bounds__(256) void gemm_kernel(
    const float* __restrict__ obs, char* __restrict__ ws) {

    __shared__ bf16x8 wefl[4 * NT * 64];   // 40 KB: one K-half of W' fragments

    const __bf16*   wefg = (const __bf16*)(ws + WEF_OFF);
    const unsigned* ordu = (const unsigned*)(ws + ORD_OFF);
    const int tid = threadIdx.x;
    const int l   = tid & 63;
    const int pw0 = blockIdx.x * 128 + (tid >> 6) * 32;   // sorted-position window
    const int q8  = (l >> 4) << 3;

    const unsigned r0 = ordu[pw0 + (l & 15)];             // natural rows to gather
    const unsigned r1 = ordu[pw0 + 16 + (l & 15)];

    f32x4 acc[2][NT];
#pragma unroll
    for (int a = 0; a < 2; ++a)
#pragma unroll
        for (int b = 0; b < NT; ++b) acc[a][b] = (f32x4){0.f, 0.f, 0.f, 0.f};

    const float* o0 = obs + (((size_t)r0) << 8) + q8;
    const float* o1 = obs + (((size_t)r1) << 8) + q8;

#pragma unroll
    for (int hf = 0; hf < 2; ++hf) {
        if (hf) __syncthreads();           // all waves done with previous half
#pragma unroll
        for (int i = 0; i < 10; ++i)       // stage 40KB: 2560 x 16B, coalesced
            wefl[i * 256 + tid] = *(const bf16x8*)(wefg + ((size_t)(hf * 2560 + i * 256 + tid)) * 8);
        __syncthreads();

#pragma unroll
        for (int g = 0; g < 4; ++g) {
            const int gg = hf * 4 + g;
            const f32x4 oa0 = *(const f32x4*)(o0 + gg * 32);
            const f32x4 ob0 = *(const f32x4*)(o0 + gg * 32 + 4);
            const f32x4 oa1 = *(const f32x4*)(o1 + gg * 32);
            const f32x4 ob1 = *(const f32x4*)(o1 + gg * 32 + 4);
            bf16x8 A0, A1;
#pragma unroll
            for (int i = 0; i < 4; ++i) {
                A0[i] = (__bf16)oa0[i];  A0[4 + i] = (__bf16)ob0[i];
                A1[i] = (__bf16)oa1[i];  A1[4 + i] = (__bf16)ob1[i];
            }
#pragma unroll
            for (int nt = 0; nt < NT; ++nt) {
                const bf16x8 bb = wefl[((g * NT + nt) << 6) + l];
                acc[0][nt] = __builtin_amdgcn_mfma_f32_16x16x32_bf16(A0, bb, acc[0][nt], 0, 0, 0);
                acc[1][nt] = __builtin_amdgcn_mfma_f32_16x16x32_bf16(A1, bb, acc[1][nt], 0, 0, 0);
            }
        }
    }

    unsigned* su  = (unsigned*)(ws + SU_OFF);
    unsigned* smu = (unsigned*)(ws + SMU_OFF);

    const int cgrp = (l >> 4) << 2;
    const int c16  = l & 15;
#pragma unroll
    for (int rt = 0; rt < 2; ++rt) {
#pragma unroll
        for (int j = 0; j < 4; ++j) {
            const int dp = pw0 + rt * 16 + cgrp + j;       // dest = sorted position
#pragma unroll
            for (int nt = 0; nt < 4; ++nt)
                su[((size_t)dp << 6) + (nt << 4) + c16] = pack2(acc[rt][nt][j], acc[rt][5 + nt][j]);
            if (c16 == 0) smu[dp] = pack2(acc[rt][4][j], acc[rt][9][j]);
        }
    }
}

// tail: one wave per bucket. Phase 1: contiguous segment-sum of y2 (hi halves of su)
// -> in-register means. Phase 2: final math from lo halves (sE); write g_n / e_n.
__global__ __launch_bounds__(256) void tail_kernel(
    const float* __restrict__ mask, const float* __restrict__ bmp,
    const float* __restrict__ bep, const char* __restrict__ ws,
    float* __restrict__ out) {

    const int bucket = blockIdx.x * 4 + (threadIdx.x >> 6);
    const int l  = threadIdx.x & 63;
    const int lc = l & 31;          // col pair (2lc, 2lc+1)
    const int hi = l >> 5;          // member parity

    const uint2 sg = ((const uint2*)(ws + SEG_OFF))[bucket];
    const unsigned start = sg.x, len = sg.y;
    if (len == 0) return;                              // wave-uniform, safe

    const unsigned* su  = (const unsigned*)(ws + SU_OFF);
    const unsigned* smu = (const unsigned*)(ws + SMU_OFF);

    float ax = 0.f, ay = 0.f;
    for (unsigned i = hi; i < len; i += 2) {
        const uint2 p = *(const uint2*)(su + (((size_t)(start + i)) << 6) + 2 * lc);
        ax += bfhi(p.x); ay += bfhi(p.y);
    }
    ax += __shfl_xor(ax, 32);
    ay += __shfl_xor(ay, 32);

    float mm = 0.f;
    for (unsigned i = l; i < len; i += 64) mm += bfhi(smu[start + i]);
#pragma unroll
    for (int off = 1; off < 64; off <<= 1) mm += __shfl_xor(mm, off);

    const float inv = 1.f / (float)len;
    const float meL = ax * inv, meH = ay * inv, mM = mm * inv;
    const float bm  = bmp[0];
    const float beL = bep[2 * lc], beH = bep[2 * lc + 1];

    const unsigned* ordu = (const unsigned*)(ws + ORD_OFF);

    for (unsigned i = hi; i < len; i += 2) {
        const unsigned d   = start + i;
        const unsigned row = ordu[d];
        const uint2 p = *(const uint2*)(su + (((size_t)d) << 6) + 2 * lc);
        const float sm = bflo(smu[d]);
        const float mk = mask[row];
        const float m  = sm - mM + bm;
        const float g  = mk / (1.f + __expf(-m));
        float2 e;
        e.x = (bflo(p.x) - meL + beL) * g * mk;
        e.y = (bflo(p.y) - meH + beH) * g * mk;
        *(float2*)(out + (size_t)ROWS + ((size_t)row << 6) + 2 * lc) = e;
        if (lc == 0) out[row] = g;
    }
}

extern "C" void kernel_launch(void* const* d_in, const int* in_sizes, int n_in,
                              void* d_out, int out_size, void* d_ws, size_t ws_size,
                              hipStream_t stream) {
    (void)in_sizes; (void)n_in; (void)out_size; (void)ws_size;
    const float* obs  = (const float*)d_in[0];
    const float* mask = (const float*)d_in[1];
    // d_in[2] = incidence: one-hot of idx, never read (saves 268 MB of traffic)
    const int*   idx  = (const int*)d_in[3];
    const float* w_m  = (const float*)d_in[4];
    const float* b_m  = (const float*)d_in[5];
    const float* w_e  = (const float*)d_in[6];
    const float* b_e  = (const float*)d_in[7];

    char* ws = (char*)d_ws;

    bucketize_kernel<<<13, 1024, 0, stream>>>(idx, w_e, w_m, ws);
    gemm_kernel<<<ROWS / 128, 256, 0, stream>>>(obs, ws);
    tail_kernel<<<BE / 4, 256, 0, stream>>>(mask, b_m, b_e, ws, (float*)d_out);
}